// Round 1
// 3731.902 us; speedup vs baseline: 1.2754x; 1.2754x over previous
//
#include <hip/hip_runtime.h>
#include <hip/hip_bf16.h>

#define TT   1024    // time steps (32x32 raster)
#define KPAD 1088    // 64 (x padded from 48) + 512 (prev2) + 512 (h)
#define LSTR 520     // LDS stage row stride in shorts (512 + 8): 260 dw ≡ 4 mod 32 -> 2-way banks (free)

typedef __attribute__((ext_vector_type(8))) short short8;
typedef __attribute__((ext_vector_type(4))) float floatx4;
using bf16 = __hip_bfloat16;

__device__ __forceinline__ float frcp(float x) { return __builtin_amdgcn_rcpf(x); }
__device__ __forceinline__ float fsig(float x) { return frcp(1.f + __expf(-x)); }
__device__ __forceinline__ float ftanh(float x) {
    float e = __expf(2.f * fminf(fmaxf(x, -15.f), 15.f));
    return (e - 1.f) * frcp(e + 1.f);
}

// 16B coherence-point load (sc0 sc1 = bypass L1/L2). The loaded data is
// quiescent once its producer flag is set, so a non-atomic wide load is safe
// (no tearing possible). MUST s_waitcnt vmcnt manually before using result.
__device__ __forceinline__ short8 sc_load16(const short* p) {
    short8 v;
    asm volatile("global_load_dwordx4 %0, %1, off sc0 sc1" : "=v"(v) : "v"(p) : "memory");
    return v;
}
__device__ __forceinline__ void wait_vm0() {
    asm volatile("s_waitcnt vmcnt(0)" ::: "memory");
    __builtin_amdgcn_sched_barrier(0);   // rule #18: fence the machine scheduler too
}

// Build combined bf16 weight matrix Wc[row][k], k: [0,48)=W_ih x-part, [48,64)=0,
// [64,576)=W_ih prev2-part, [576,1088)=W_hh. Also bias = b_ih + b_hh (fp32).
__global__ void prep_wb(const float* __restrict__ Wih, const float* __restrict__ Whh,
                        const float* __restrict__ bih, const float* __restrict__ bhh,
                        bf16* __restrict__ Wc, float* __restrict__ bias) {
    int idx = blockIdx.x * 256 + threadIdx.x;
    int total = 2048 * KPAD;
    if (idx < total) {
        int row = idx / KPAD;
        int k = idx - row * KPAD;
        float v = 0.f;
        if (k < 48)       v = Wih[row * 560 + k];
        else if (k < 64)  v = 0.f;
        else if (k < 576) v = Wih[row * 560 + 48 + (k - 64)];
        else              v = Whh[row * 512 + (k - 576)];
        Wc[idx] = __float2bfloat16(v);
    }
    if (idx < 2048) bias[idx] = bih[idx] + bhh[idx];
}

// Extract patches: xs[t][b][kk] (kk = c*16 + py*4 + px, padded 48->64 with zeros), bf16.
__global__ void prep_x(const float* __restrict__ batch, bf16* __restrict__ xs) {
    int idx = blockIdx.x * 256 + threadIdx.x;   // exactly 1024*64*64 threads
    int kk = idx & 63;
    int b  = (idx >> 6) & 63;
    int t  = idx >> 12;
    float v = 0.f;
    if (kk < 48) {
        int c = kk >> 4, py = (kk >> 2) & 3, px = kk & 3;
        int i = t >> 5, j = t & 31;
        v = batch[((b * 3 + c) * 128 + (i * 4 + py)) * 128 + (j * 4 + px)];
    }
    xs[idx] = __float2bfloat16(v);
}

// Persistent 2D-LSTM. 128 WGs = 4 independent batch-groups x 32 cell-chunk WGs.
// Wave w = gate w for the WG's 16 cells over 16 batches (mfma 16x16x32 bf16).
// Weights pinned in VGPRs (34 short8 frags per lane).
//
// Cross-WG exchange redesign vs previous version:
//  - per-WG monotonic flag (32 dwords = one 128B line per group), plain atomic
//    store; NO fetch_add RMW serialization.
//  - all 4 waves poll flags autonomously (64-lane vector load + __any); no
//    tid0-spin + syncthreads release hop.
//  - h / prev2 staged with lane-contiguous 16B sc0sc1 loads (coalesced, ~32
//    txns/WG/step vs ~512 8B-atomic txns before).
//  - prev2 double-buffered and prefetched one step early: off critical path.
//  - cell phase on wave 0 only (4 cells/lane): h-store -> wave-local
//    s_waitcnt vmcnt(0) -> flag store, no workgroup barrier in producer path.
//  - 2 barriers/step (was 5). Hazard analysis: hbuf writes at (e)(t) are past
//    B2(t-1) so all Phase-B(t-1) reads done; gsm writes at (g)(t) are past
//    B1(t) which wave 0 only reaches after its cell(t-1) gsm reads.
__launch_bounds__(256, 1)
__global__ void lstm_persist(const bf16* __restrict__ Wc, const float* __restrict__ bias,
                             const bf16* __restrict__ xs, bf16* __restrict__ ring,
                             float* __restrict__ out, unsigned* __restrict__ flags)
{
    __shared__ float gsm[4][16][20];       // [gate][batch][cell], 20 dw rows: 16B-aligned b128 reads
    __shared__ short p2buf[2][16 * LSTR];  // prev2 double buffer (prefetched 1 step ahead)
    __shared__ short hbuf[16 * LSTR];      // h(t-1) stage

    const int wg   = blockIdx.x;
    const int bg   = wg >> 5;          // batch group 0..3
    const int wgc  = wg & 31;          // cell chunk 0..31
    const int tid  = threadIdx.x;
    const int w    = tid >> 6;         // wave id == gate id 0..3
    const int lane = tid & 63;
    const int mrow = lane & 15;        // A: batch-in-16; B/D: cell-in-16
    const int quad = lane >> 4;

    // ---- weights -> VGPRs, pinned so they can't be rematerialized ----
    const int grow = w * 512 + wgc * 16 + mrow;     // global gate row
    short8 wf[34];
    {
        const short* wsrc = (const short*)Wc + (size_t)grow * KPAD + quad * 8;
        #pragma unroll
        for (int i = 0; i < 34; ++i) wf[i] = *(const short8*)(wsrc + i * 32);
        #pragma unroll
        for (int i = 0; i < 34; ++i) { asm volatile("" : "+v"(wf[i])); }
    }
    const float bias_r = bias[grow];

    unsigned* gflags = flags + bg * 32;            // one 128B line per group
    const short* ringS = (const short*)ring;

    // staging role: wave w stages batch rows 4w..4w+3; lane L = 16B chunk L of a row.
    // Global loads are lane-contiguous (1KB per wave-instr, fully coalesced);
    // LDS writes land 2-way-banked (free).
    const int srow = 4 * w;                        // first staged batch row
    // c-state: wave 0, lane l owns batch l>>2, cells 4*(l&3)..+4
    floatx4 cst = {0.f, 0.f, 0.f, 0.f};

    // ---- prologue: p2buf[0] = zeros (prev2 for t=0 is h(-32) = 0) ----
    {
        short8 z = {0, 0, 0, 0, 0, 0, 0, 0};
        short* pd = &p2buf[0][srow * LSTR + lane * 8];
        #pragma unroll
        for (int j = 0; j < 4; ++j) *(short8*)(pd + j * LSTR) = z;
    }
    __syncthreads();

    for (int t = 0; t < TT; ++t) {
        // ---- (a) Phase A: x + prev2 partial gates (independent of h(t-1)) ----
        floatx4 acc[4];
        #pragma unroll
        for (int r = 0; r < 4; ++r) acc[r] = (floatx4){0.f, 0.f, 0.f, 0.f};
        {
            const short* xrow = (const short*)xs + ((size_t)t * 64 + bg * 16 + mrow) * 64 + quad * 8;
            short8 xa0 = *(const short8*)(xrow);
            short8 xa1 = *(const short8*)(xrow + 32);
            acc[0] = __builtin_amdgcn_mfma_f32_16x16x32_bf16(xa0, wf[0], acc[0], 0, 0, 0);
            acc[1] = __builtin_amdgcn_mfma_f32_16x16x32_bf16(xa1, wf[1], acc[1], 0, 0, 0);
            const short* pb = &p2buf[t & 1][mrow * LSTR + quad * 8];
            #pragma unroll
            for (int i = 0; i < 16; ++i) {
                short8 a = *(const short8*)(pb + i * 32);
                acc[(2 + i) & 3] = __builtin_amdgcn_mfma_f32_16x16x32_bf16(a, wf[2 + i], acc[(2 + i) & 3], 0, 0, 0);
            }
        }

        // ---- (b) poll: all waves wait until every WG in group finished t-1 ----
        if (t) {
            const unsigned tgt = (unsigned)t;
            unsigned v;
            do {
                v = __hip_atomic_load(gflags + (lane & 31), __ATOMIC_RELAXED, __HIP_MEMORY_SCOPE_AGENT);
            } while (__any((int)(v < tgt)));
        }

        // ---- (c)(d) coherence-point loads: h(t-1) + prefetch prev2 for t+1 ----
        short8 hv[4], pv[4];
        {
            const short* hb = ringS + ((size_t)(((t + 31) & 63) * 64 + bg * 16)) * 512 + w * 2048 + lane * 8;
            #pragma unroll
            for (int j = 0; j < 4; ++j) hv[j] = sc_load16(hb + j * 512);
            const short* p2 = ringS + ((size_t)(((t + 1) & 63) * 64 + bg * 16)) * 512 + w * 2048 + lane * 8;
            #pragma unroll
            for (int j = 0; j < 4; ++j) pv[j] = sc_load16(p2 + j * 512);
        }
        // ---- (e) drain and write to LDS ----
        wait_vm0();
        {
            short* hd = &hbuf[srow * LSTR + lane * 8];
            #pragma unroll
            for (int j = 0; j < 4; ++j) *(short8*)(hd + j * LSTR) = hv[j];
            short* pd = &p2buf[(t + 1) & 1][srow * LSTR + lane * 8];
            #pragma unroll
            for (int j = 0; j < 4; ++j) *(short8*)(pd + j * LSTR) = pv[j];
        }
        __syncthreads();   // B1: hbuf/p2buf visible to all waves

        // ---- (g) Phase B: h(t-1) MFMAs ----
        {
            const short* hbp = &hbuf[mrow * LSTR + quad * 8];
            #pragma unroll
            for (int i = 0; i < 16; ++i) {
                short8 a = *(const short8*)(hbp + i * 32);
                acc[(18 + i) & 3] = __builtin_amdgcn_mfma_f32_16x16x32_bf16(a, wf[18 + i], acc[(18 + i) & 3], 0, 0, 0);
            }
        }
        floatx4 s = acc[0] + acc[1] + acc[2] + acc[3];
        #pragma unroll
        for (int r = 0; r < 4; ++r) gsm[w][quad * 4 + r][mrow] = s[r] + bias_r;
        __syncthreads();   // B2: gsm visible to wave 0

        // ---- (i) cell phase: wave 0 only, 4 cells/lane; producer signal path ----
        if (w == 0) {
            const int cm  = lane >> 2;          // batch in 16
            const int cj4 = (lane & 3) * 4;     // first cell of 4
            floatx4 gi = *(const floatx4*)&gsm[0][cm][cj4];
            floatx4 gf = *(const floatx4*)&gsm[1][cm][cj4];
            floatx4 gg = *(const floatx4*)&gsm[2][cm][cj4];
            floatx4 go = *(const floatx4*)&gsm[3][cm][cj4];
            union { unsigned long long u; unsigned short sh[4]; } hp;
            floatx4 hh;
            #pragma unroll
            for (int k = 0; k < 4; ++k) {
                float c = fsig(gf[k]) * cst[k] + fsig(gi[k]) * ftanh(gg[k]);
                cst[k] = c;
                float h = fsig(go[k]) * ftanh(c);
                hh[k] = h;
                union { bf16 b; unsigned short u; } cv;
                cv.b = __float2bfloat16(h);
                hp.sh[k] = cv.u;
            }
            short* hst = (short*)ring + ((size_t)(((t + 32) & 63) * 64 + bg * 16 + cm)) * 512 + wgc * 16 + cj4;
            __hip_atomic_store((unsigned long long*)hst, hp.u, __ATOMIC_RELAXED, __HIP_MEMORY_SCOPE_AGENT);
            // wave-local ack of the 64 h-stores, then signal; out-store AFTER the
            // flag so vmcnt(0) doesn't wait on the (slow, consumer-less) out write.
            asm volatile("s_waitcnt vmcnt(0)" ::: "memory");
            __builtin_amdgcn_sched_barrier(0);
            if (lane == 0)
                __hip_atomic_store(gflags + wgc, (unsigned)(t + 1), __ATOMIC_RELAXED, __HIP_MEMORY_SCOPE_AGENT);
            *(floatx4*)(out + (size_t)(bg * 16 + cm) * TT * 512 + (size_t)t * 512 + wgc * 16 + cj4) = hh;
        }
        // no trailing barrier: waves 1..3 run ahead into Phase A(t+1)/poll(t+1);
        // all LDS hazards covered by B1/B2 (see header comment).
    }
}

extern "C" void kernel_launch(void* const* d_in, const int* in_sizes, int n_in,
                              void* d_out, int out_size, void* d_ws, size_t ws_size,
                              hipStream_t stream) {
    const float* batch = (const float*)d_in[0];
    const float* Wih   = (const float*)d_in[1];
    const float* Whh   = (const float*)d_in[2];
    const float* bih   = (const float*)d_in[3];
    const float* bhh   = (const float*)d_in[4];
    float* out = (float*)d_out;

    char* p = (char*)d_ws;
    bf16*  Wc     = (bf16*)p;     p += (size_t)2048 * KPAD * 2;          // 4,456,448
    float* bias   = (float*)p;    p += (size_t)2048 * 4;                 // 8,192
    bf16*  xs     = (bf16*)p;     p += (size_t)TT * 64 * 64 * 2;         // 8,388,608
    bf16*  ring   = (bf16*)p;     p += (size_t)64 * 64 * 512 * 2;        // 4,194,304
    unsigned* flg = (unsigned*)p; p += 512;                              // 4 groups x 128B flag lines

    // zero ring slots 0..31 (prev2 for t<32, h(-1) at slot 31) and flags
    hipMemsetAsync(ring, 0, (size_t)32 * 64 * 512 * 2, stream);
    hipMemsetAsync(flg, 0, 512, stream);

    prep_wb<<<(2048 * KPAD + 255) / 256, 256, 0, stream>>>(Wih, Whh, bih, bhh, Wc, bias);
    prep_x<<<(TT * 64 * 64) / 256, 256, 0, stream>>>(batch, xs);

    lstm_persist<<<128, 256, 0, stream>>>(Wc, bias, xs, ring, out, flg);
}

// Round 2
// 2901.910 us; speedup vs baseline: 1.6401x; 1.2860x over previous
//
#include <hip/hip_runtime.h>
#include <hip/hip_bf16.h>

#define TT   1024    // time steps (32x32 raster)
#define KPAD 1088    // 64 (x padded from 48) + 512 (prev2) + 512 (h)
#define LSTR 520     // LDS stage row stride in shorts (512 + 8): 2-way banks (free)

typedef __attribute__((ext_vector_type(8))) short short8;
typedef __attribute__((ext_vector_type(4))) float floatx4;
using bf16 = __hip_bfloat16;

__device__ __forceinline__ float frcp(float x) { return __builtin_amdgcn_rcpf(x); }
__device__ __forceinline__ float fsig(float x) { return frcp(1.f + __expf(-x)); }
__device__ __forceinline__ float ftanh(float x) {
    float e = __expf(2.f * fminf(fmaxf(x, -15.f), 15.f));
    return (e - 1.f) * frcp(e + 1.f);
}

// 16B coherence-point load (sc0 sc1). Data is quiescent once its producer flag
// is set, so a non-atomic wide load is safe. Must s_waitcnt vmcnt manually.
__device__ __forceinline__ short8 sc_load16(const short* p) {
    short8 v;
    asm volatile("global_load_dwordx4 %0, %1, off sc0 sc1" : "=v"(v) : "v"(p) : "memory");
    return v;
}
__device__ __forceinline__ void wait_vm0() {
    asm volatile("s_waitcnt vmcnt(0)" ::: "memory");
    __builtin_amdgcn_sched_barrier(0);   // rule #18
}

// Build combined bf16 weight matrix Wc[row][k], k: [0,48)=W_ih x-part, [48,64)=0,
// [64,576)=W_ih prev2-part, [576,1088)=W_hh. Also bias = b_ih + b_hh (fp32).
__global__ void prep_wb(const float* __restrict__ Wih, const float* __restrict__ Whh,
                        const float* __restrict__ bih, const float* __restrict__ bhh,
                        bf16* __restrict__ Wc, float* __restrict__ bias) {
    int idx = blockIdx.x * 256 + threadIdx.x;
    int total = 2048 * KPAD;
    if (idx < total) {
        int row = idx / KPAD;
        int k = idx - row * KPAD;
        float v = 0.f;
        if (k < 48)       v = Wih[row * 560 + k];
        else if (k < 64)  v = 0.f;
        else if (k < 576) v = Wih[row * 560 + 48 + (k - 64)];
        else              v = Whh[row * 512 + (k - 576)];
        Wc[idx] = __float2bfloat16(v);
    }
    if (idx < 2048) bias[idx] = bih[idx] + bhh[idx];
}

// Extract patches: xs[t][b][kk] (kk = c*16 + py*4 + px, padded 48->64), bf16.
__global__ void prep_x(const float* __restrict__ batch, bf16* __restrict__ xs) {
    int idx = blockIdx.x * 256 + threadIdx.x;   // exactly 1024*64*64 threads
    int kk = idx & 63;
    int b  = (idx >> 6) & 63;
    int t  = idx >> 12;
    float v = 0.f;
    if (kk < 48) {
        int c = kk >> 4, py = (kk >> 2) & 3, px = kk & 3;
        int i = t >> 5, j = t & 31;
        v = batch[((b * 3 + c) * 128 + (i * 4 + py)) * 128 + (j * 4 + px)];
    }
    xs[idx] = __float2bfloat16(v);
}

// Persistent 2D-LSTM. 64 WGs x 512 threads = 4 batch-groups x 16 cell-chunk WGs.
// Wave w (8/WG): gate (w&3), cell-sub (w>>2); computes 16 cells x 16 batches of
// one gate per step (mfma 16x16x32 bf16, 34 weight frags pinned in regs).
//
// Changes vs previous round (contention/straggler attack):
//  - 16 WGs per group (was 32): halves straggler pool + coherence h-traffic.
//  - ONE polling wave per WG (wave 7) + s_barrier release (was all waves
//    polling one line): 64 pollers device-wide, was 512.
//  - flags spread 64B apart (32 x 64B per group): producer stores don't all
//    collide on one line with every poll read.
//  - per-cell-wave flags (2/WG): each producer does store->vmcnt(0)->flag
//    with no intra-WG coordination.
//  - prev2 prefetch issued at top of iteration, drained together with h.
// Barrier/hazard analysis (3 barriers/step: B0 poll-release, B1 stage, B2 gsm):
//  - hbuf writes (d)(t+1) vs Phase-B reads (f)(t): separated by B2(g)(t).
//  - p2buf[par] writes (d)(t+1) vs reads (a)(t): separated by B0(b)(t+1)
//    arrival ordering (all waves passed their (a)(t) before anyone passes B0(t+1)).
//  - gsm writes (f)(t+1) vs cell reads (h)(t): separated by B1(e)(t+1).
__launch_bounds__(512, 1)
__global__ void lstm_persist(const bf16* __restrict__ Wc, const float* __restrict__ bias,
                             const bf16* __restrict__ xs, bf16* __restrict__ ring,
                             float* __restrict__ out, unsigned* __restrict__ flags)
{
    __shared__ float gsm[4][16][36];       // [gate][batch][cell-in-32], 36: 16B-aligned rows, 2-way banks
    __shared__ short p2buf[2][16 * LSTR];  // prev2 double buffer (prefetched 1 step ahead)
    __shared__ short hbuf[16 * LSTR];      // h(t-1) stage

    const int wg   = blockIdx.x;
    const int bg   = wg & 3;           // batch group 0..3 (round-robin: group spans ~2 XCDs)
    const int wgc  = wg >> 2;          // cell chunk 0..15 (32 cells each)
    const int tid  = threadIdx.x;
    const int w    = tid >> 6;         // wave 0..7
    const int lane = tid & 63;
    const int mrow = lane & 15;        // A: batch-in-16; B/D: cell-in-16
    const int quad = lane >> 4;
    const int gate = w & 3;
    const int sc   = w >> 2;           // cell-sub 0..1

    // ---- weights -> VGPRs, pinned ----
    const int grow = gate * 512 + wgc * 32 + sc * 16 + mrow;   // global gate row
    short8 wf[34];
    {
        const short* wsrc = (const short*)Wc + (size_t)grow * KPAD + quad * 8;
        #pragma unroll
        for (int i = 0; i < 34; ++i) wf[i] = *(const short8*)(wsrc + i * 32);
        #pragma unroll
        for (int i = 0; i < 34; ++i) { asm volatile("" : "+v"(wf[i])); }
    }
    const float bias_r = bias[grow];

    unsigned* gflags = flags + bg * 512;   // 32 flags x 16 dwords (64B apart)
    const short* ringS = (const short*)ring;

    // staging role: wave w stages batch rows 2w, 2w+1; lane = 16B chunk of row.
    const int r0 = 2 * w;
    // c-state: waves 0,1; lane l owns batch 8w+(l>>3), cells (l&7)*4 .. +4
    floatx4 cst = {0.f, 0.f, 0.f, 0.f};

    // ---- prologue: p2buf[0] = zeros (prev2 for t=0 is h(-32) = 0) ----
    {
        short8 z = {0, 0, 0, 0, 0, 0, 0, 0};
        *(short8*)&p2buf[0][(r0 + 0) * LSTR + lane * 8] = z;
        *(short8*)&p2buf[0][(r0 + 1) * LSTR + lane * 8] = z;
    }
    __syncthreads();

    for (int t = 0; t < TT; ++t) {
        // ---- (a0) prefetch prev2 for t+1 (ready for 31+ steps; off critical path) ----
        short8 pv0, pv1;
        {
            const short* p2 = ringS + ((size_t)(((t + 1) & 63) * 64 + bg * 16 + r0)) * 512 + lane * 8;
            pv0 = sc_load16(p2);
            pv1 = sc_load16(p2 + 512);
        }

        // ---- (a) Phase A: x + prev2 partial gates (independent of h(t-1)) ----
        floatx4 acc[4];
        #pragma unroll
        for (int r = 0; r < 4; ++r) acc[r] = (floatx4){0.f, 0.f, 0.f, 0.f};
        {
            const short* xrow = (const short*)xs + ((size_t)t * 64 + bg * 16 + mrow) * 64 + quad * 8;
            short8 xa0 = *(const short8*)(xrow);
            short8 xa1 = *(const short8*)(xrow + 32);
            acc[0] = __builtin_amdgcn_mfma_f32_16x16x32_bf16(xa0, wf[0], acc[0], 0, 0, 0);
            acc[1] = __builtin_amdgcn_mfma_f32_16x16x32_bf16(xa1, wf[1], acc[1], 0, 0, 0);
            const short* pb = &p2buf[t & 1][mrow * LSTR + quad * 8];
            #pragma unroll
            for (int i = 0; i < 16; ++i) {
                short8 a = *(const short8*)(pb + i * 32);
                acc[(2 + i) & 3] = __builtin_amdgcn_mfma_f32_16x16x32_bf16(a, wf[2 + i], acc[(2 + i) & 3], 0, 0, 0);
            }
        }

        // ---- (b) B0: wave 7 polls all 32 group flags >= t; barrier releases WG ----
        if (t) {
            if (w == 7) {
                const unsigned tgt = (unsigned)t;
                unsigned v;
                do {
                    v = __hip_atomic_load(gflags + (lane & 31) * 16, __ATOMIC_RELAXED, __HIP_MEMORY_SCOPE_AGENT);
                } while (__any((int)(v < tgt)));
            }
            __syncthreads();
        }

        // ---- (c) coherence-point h(t-1) loads (2 coalesced 1KB wave-loads) ----
        short8 hv0, hv1;
        {
            const short* hb = ringS + ((size_t)(((t + 31) & 63) * 64 + bg * 16 + r0)) * 512 + lane * 8;
            hv0 = sc_load16(hb);
            hv1 = sc_load16(hb + 512);
        }
        // ---- (d) drain, write LDS stages ----
        wait_vm0();
        *(short8*)&hbuf[(r0 + 0) * LSTR + lane * 8] = hv0;
        *(short8*)&hbuf[(r0 + 1) * LSTR + lane * 8] = hv1;
        {
            short* pd = &p2buf[(t + 1) & 1][0];
            *(short8*)&pd[(r0 + 0) * LSTR + lane * 8] = pv0;
            *(short8*)&pd[(r0 + 1) * LSTR + lane * 8] = pv1;
        }
        __syncthreads();   // (e) B1: hbuf/p2buf visible

        // ---- (f) Phase B: h(t-1) MFMAs ----
        {
            const short* hbp = &hbuf[mrow * LSTR + quad * 8];
            #pragma unroll
            for (int i = 0; i < 16; ++i) {
                short8 a = *(const short8*)(hbp + i * 32);
                acc[(18 + i) & 3] = __builtin_amdgcn_mfma_f32_16x16x32_bf16(a, wf[18 + i], acc[(18 + i) & 3], 0, 0, 0);
            }
        }
        floatx4 s = acc[0] + acc[1] + acc[2] + acc[3];
        #pragma unroll
        for (int r = 0; r < 4; ++r) gsm[gate][quad * 4 + r][sc * 16 + mrow] = s[r] + bias_r;
        __syncthreads();   // (g) B2: gsm visible to cell waves

        // ---- (h) cell phase: waves 0,1 (4 cells/lane); others run ahead ----
        if (w < 2) {
            const int b16 = 8 * w + (lane >> 3);    // batch in 16
            const int cj  = (lane & 7) * 4;         // first cell of 4 (in 32)
            floatx4 gi = *(const floatx4*)&gsm[0][b16][cj];
            floatx4 gf = *(const floatx4*)&gsm[1][b16][cj];
            floatx4 gg = *(const floatx4*)&gsm[2][b16][cj];
            floatx4 go = *(const floatx4*)&gsm[3][b16][cj];
            union { unsigned long long u; unsigned short sh[4]; } hp;
            floatx4 hh;
            #pragma unroll
            for (int k = 0; k < 4; ++k) {
                float c = fsig(gf[k]) * cst[k] + fsig(gi[k]) * ftanh(gg[k]);
                cst[k] = c;
                float h = fsig(go[k]) * ftanh(c);
                hh[k] = h;
                union { bf16 b; unsigned short u; } cv;
                cv.b = __float2bfloat16(h);
                hp.sh[k] = cv.u;
            }
            short* hst = (short*)ring + ((size_t)(((t + 32) & 63) * 64 + bg * 16 + b16)) * 512
                         + wgc * 32 + cj;
            __hip_atomic_store((unsigned long long*)hst, hp.u, __ATOMIC_RELAXED, __HIP_MEMORY_SCOPE_AGENT);
            // wave-local ack of this wave's h stores, then its own flag.
            asm volatile("s_waitcnt vmcnt(0)" ::: "memory");
            __builtin_amdgcn_sched_barrier(0);
            if (lane == 0)
                __hip_atomic_store(gflags + (wgc * 2 + w) * 16, (unsigned)(t + 1),
                                   __ATOMIC_RELAXED, __HIP_MEMORY_SCOPE_AGENT);
            // out store after the flag so vmcnt(0) never waits on it.
            *(floatx4*)(out + (size_t)(bg * 16 + b16) * TT * 512 + (size_t)t * 512 + wgc * 32 + cj) = hh;
        }
        // no trailing barrier: waves 2..7 run ahead into (a0)/(a)/(b) of t+1.
    }
}

extern "C" void kernel_launch(void* const* d_in, const int* in_sizes, int n_in,
                              void* d_out, int out_size, void* d_ws, size_t ws_size,
                              hipStream_t stream) {
    const float* batch = (const float*)d_in[0];
    const float* Wih   = (const float*)d_in[1];
    const float* Whh   = (const float*)d_in[2];
    const float* bih   = (const float*)d_in[3];
    const float* bhh   = (const float*)d_in[4];
    float* out = (float*)d_out;

    char* p = (char*)d_ws;
    bf16*  Wc     = (bf16*)p;     p += (size_t)2048 * KPAD * 2;          // 4,456,448
    float* bias   = (float*)p;    p += (size_t)2048 * 4;                 // 8,192
    bf16*  xs     = (bf16*)p;     p += (size_t)TT * 64 * 64 * 2;         // 8,388,608
    bf16*  ring   = (bf16*)p;     p += (size_t)64 * 64 * 512 * 2;        // 4,194,304
    unsigned* flg = (unsigned*)p; p += 8192;                             // 4 groups x 32 flags x 64B

    // zero ring slots 0..31 (prev2 for t<32, h(-1) at slot 31) and flags
    hipMemsetAsync(ring, 0, (size_t)32 * 64 * 512 * 2, stream);
    hipMemsetAsync(flg, 0, 8192, stream);

    prep_wb<<<(2048 * KPAD + 255) / 256, 256, 0, stream>>>(Wih, Whh, bih, bhh, Wc, bias);
    prep_x<<<(TT * 64 * 64) / 256, 256, 0, stream>>>(batch, xs);

    lstm_persist<<<64, 512, 0, stream>>>(Wc, bias, xs, ring, out, flg);
}